// Round 2
// 718.999 us; speedup vs baseline: 1.0186x; 1.0186x over previous
//
#include <hip/hip_runtime.h>

typedef __bf16 bf16x8 __attribute__((ext_vector_type(8)));
typedef float floatx4 __attribute__((ext_vector_type(4)));

#define NPB 256        // nodes per bucket (power of 2)
#define NPB_SHIFT 8
#define MAXNB 1024     // max buckets supported (N <= 262144)
#define TILE 4096      // edges per binning block (391 blocks @ E=1.6M -> all CUs busy)

static __device__ __forceinline__ float bfu_to_f(unsigned short u) {
    unsigned int x = ((unsigned int)u) << 16;
    return __builtin_bit_cast(float, x);
}
static __device__ __forceinline__ unsigned short f_to_bfu(float f) {
    unsigned int u = __builtin_bit_cast(unsigned int, f);
    unsigned int r = (u + 0x7fffu + ((u >> 16) & 1u)) >> 16;
    return (unsigned short)r;
}

// ---------------- dtype detection ----------------
__global__ void detect_k(const unsigned short* __restrict__ bih_u,
                         const unsigned int* __restrict__ ei_u,
                         int* __restrict__ flags) {
    if (threadIdx.x == 0 && blockIdx.x == 0) {
        int votes = 0;
        for (int i = 0; i < 64; i++) {
            unsigned short u = bih_u[2 * i];
            unsigned int ex = (u >> 7) & 0xFF;
            if (ex >= 64 && ex < 124) votes++;
        }
        flags[0] = (votes >= 48) ? 1 : 0;
        int zeros = 0;
        for (int i = 0; i < 64; i++) {
            if (ei_u[2 * i + 1] == 0u) zeros++;
        }
        flags[1] = (zeros == 64) ? 1 : 0;
    }
}

// ---------------- canonicalization ----------------

__global__ void cvt_bf16_k(const void* __restrict__ in, unsigned short* __restrict__ out,
                           int n, const int* __restrict__ flags) {
    int i = blockIdx.x * 256 + threadIdx.x;
    if (i >= n) return;
    if (flags[0]) out[i] = ((const unsigned short*)in)[i];
    else out[i] = f_to_bfu(((const float*)in)[i]);
}

__global__ void cvt_bias_k(const void* __restrict__ bih, const void* __restrict__ bhh,
                           float* __restrict__ bih_f, float* __restrict__ bhh_f,
                           const int* __restrict__ flags) {
    int i = blockIdx.x * 256 + threadIdx.x;
    if (i >= 768) return;
    const void* src = (i < 384) ? bih : bhh;
    int j = (i < 384) ? i : i - 384;
    float v = flags[0] ? bfu_to_f(((const unsigned short*)src)[j]) : ((const float*)src)[j];
    if (i < 384) bih_f[j] = v;
    else bhh_f[j] = v;
}

__global__ void out_k(const unsigned short* __restrict__ xb, void* __restrict__ out,
                      int n, const int* __restrict__ flags) {
    int i = blockIdx.x * 256 + threadIdx.x;
    if (i >= n) return;
    if (flags[0]) ((unsigned short*)out)[i] = xb[i];
    else ((float*)out)[i] = bfu_to_f(xb[i]);
}

// ---------------- hierarchical CSR build ----------------

static __device__ __forceinline__ int load_idx(const unsigned int* eiu, size_t pos, int is64) {
    return (int)eiu[is64 ? 2 * pos : pos];
}

__global__ __launch_bounds__(256) void count_k(const unsigned int* __restrict__ eiu,
                                               int* __restrict__ bucketCnt, int E,
                                               const int* __restrict__ flags) {
    __shared__ int cnt[MAXNB];
    int t = threadIdx.x;
    for (int b = t; b < MAXNB; b += 256) cnt[b] = 0;
    __syncthreads();
    int is64 = flags[1];
    int e0 = blockIdx.x * TILE;
    int e1 = min(e0 + TILE, E);
    for (int e = e0 + t; e < e1; e += 256) {
        int d = load_idx(eiu, (size_t)E + e, is64);
        atomicAdd(&cnt[d >> NPB_SHIFT], 1);
    }
    __syncthreads();
    for (int b = t; b < MAXNB; b += 256) {
        int c = cnt[b];
        if (c) atomicAdd(&bucketCnt[b], c);
    }
}

__global__ void scanB_k(const int* __restrict__ bucketCnt, int* __restrict__ bucketBase,
                        int* __restrict__ bucketCursor, int NB, int E) {
    __shared__ int sh[MAXNB];
    int t = threadIdx.x;  // 1024 threads
    int v = (t < NB) ? bucketCnt[t] : 0;
    sh[t] = v;
    __syncthreads();
    for (int off = 1; off < MAXNB; off <<= 1) {
        int u = (t >= off) ? sh[t - off] : 0;
        __syncthreads();
        sh[t] += u;
        __syncthreads();
    }
    if (t < NB) {
        int b = sh[t] - v;
        bucketBase[t] = b;
        bucketCursor[t] = b;
    }
    if (t == 0) bucketBase[NB] = E;
}

__global__ __launch_bounds__(256) void bin_k(const unsigned int* __restrict__ eiu,
                                             const void* __restrict__ ew,
                                             int* __restrict__ bucketCursor,
                                             uint2* __restrict__ rec8,
                                             int* __restrict__ dstA, int E,
                                             const int* __restrict__ flags) {
    __shared__ int cnt[MAXNB];
    __shared__ int basel[MAXNB];
    int t = threadIdx.x;
    for (int b = t; b < MAXNB; b += 256) cnt[b] = 0;
    __syncthreads();
    int is64 = flags[1];
    int isb = flags[0];
    int e0 = blockIdx.x * TILE;
    int e1 = min(e0 + TILE, E);
    for (int e = e0 + t; e < e1; e += 256) {
        int d = load_idx(eiu, (size_t)E + e, is64);
        atomicAdd(&cnt[d >> NPB_SHIFT], 1);
    }
    __syncthreads();
    for (int b = t; b < MAXNB; b += 256) {
        int c = cnt[b];
        basel[b] = c ? atomicAdd(&bucketCursor[b], c) : 0;
        cnt[b] = 0;
    }
    __syncthreads();
    for (int e = e0 + t; e < e1; e += 256) {
        int s = load_idx(eiu, (size_t)e, is64);
        int d = load_idx(eiu, (size_t)E + e, is64);
        float w = isb ? bfu_to_f(((const unsigned short*)ew)[e]) : ((const float*)ew)[e];
        int b = d >> NPB_SHIFT;
        int p = basel[b] + atomicAdd(&cnt[b], 1);
        dstA[p] = d;
        rec8[p] = make_uint2((unsigned int)s, __builtin_bit_cast(unsigned int, w));
    }
}

__global__ __launch_bounds__(256) void csr_k(const uint2* __restrict__ rec8,
                                             const int* __restrict__ dstA,
                                             const int* __restrict__ bucketBase,
                                             int* __restrict__ offsets,
                                             uint2* __restrict__ rec, int N, int E) {
    __shared__ int cnt[NPB];
    __shared__ int sh[NPB];
    __shared__ int cur[NPB];
    int t = threadIdx.x;
    int b = blockIdx.x;
    int n0 = b << NPB_SHIFT;
    int nodes = min(NPB, N - n0);
    int ebase = bucketBase[b];
    int ecnt = bucketBase[b + 1] - ebase;

    cnt[t] = 0;
    __syncthreads();
    for (int i = t; i < ecnt; i += 256) {
        int d = dstA[ebase + i] - n0;
        atomicAdd(&cnt[d], 1);
    }
    __syncthreads();
    int v = cnt[t];
    sh[t] = v;
    __syncthreads();
    for (int off = 1; off < NPB; off <<= 1) {
        int u = (t >= off) ? sh[t - off] : 0;
        __syncthreads();
        sh[t] += u;
        __syncthreads();
    }
    int loff = sh[t] - v;  // exclusive
    if (t < nodes) offsets[n0 + t] = ebase + loff;
    cur[t] = ebase + loff;
    if (b == 0 && t == 0) offsets[N] = E;
    __syncthreads();
    for (int i = t; i < ecnt; i += 256) {
        int d = dstA[ebase + i] - n0;
        int p = atomicAdd(&cur[d], 1);
        rec[p] = rec8[ebase + i];
    }
}

// ---------------- Ut_l[j][a] = sum_k W_l[a][k] * w_ih[j][k] ----------------
// Vectorized: 16x uint4 (bf16) or 32x float4 (f32) loads per thread instead of
// 256 scalar 2B loads (latency-chain bound before).

static __device__ __forceinline__ float dot8_bf(uint4 wv, uint4 iv) {
    float s;
    s  = bfu_to_f((unsigned short)(wv.x)) * bfu_to_f((unsigned short)(iv.x));
    s += bfu_to_f((unsigned short)(wv.x >> 16)) * bfu_to_f((unsigned short)(iv.x >> 16));
    s += bfu_to_f((unsigned short)(wv.y)) * bfu_to_f((unsigned short)(iv.y));
    s += bfu_to_f((unsigned short)(wv.y >> 16)) * bfu_to_f((unsigned short)(iv.y >> 16));
    s += bfu_to_f((unsigned short)(wv.z)) * bfu_to_f((unsigned short)(iv.z));
    s += bfu_to_f((unsigned short)(wv.z >> 16)) * bfu_to_f((unsigned short)(iv.z >> 16));
    s += bfu_to_f((unsigned short)(wv.w)) * bfu_to_f((unsigned short)(iv.w));
    s += bfu_to_f((unsigned short)(wv.w >> 16)) * bfu_to_f((unsigned short)(iv.w >> 16));
    return s;
}

__global__ void make_ut_k(const void* __restrict__ weight, const void* __restrict__ wih,
                          unsigned short* __restrict__ Ut, const int* __restrict__ flags) {
    int idx = blockIdx.x * 256 + threadIdx.x;  // l*49152 + j*128 + a
    if (idx >= 3 * 384 * 128) return;
    int isb = flags[0];
    int a = idx & 127;
    int j = (idx >> 7) % 384;
    int l = idx / (384 * 128);
    float s = 0.f;
    if (isb) {
        const uint4* W4 = (const uint4*)((const unsigned short*)weight + (size_t)l * 16384 + a * 128);
        const uint4* I4 = (const uint4*)((const unsigned short*)wih + (size_t)j * 128);
#pragma unroll
        for (int c = 0; c < 16; c++) s += dot8_bf(W4[c], I4[c]);
    } else {
        const float4* W4 = (const float4*)((const float*)weight + (size_t)l * 16384 + a * 128);
        const float4* I4 = (const float4*)((const float*)wih + (size_t)j * 128);
#pragma unroll
        for (int c = 0; c < 32; c++) {
            float4 w = W4[c], i = I4[c];
            s += w.x * i.x + w.y * i.y + w.z * i.z + w.w * i.w;
        }
    }
    Ut[idx] = f_to_bfu(s);
}

// ---------------- pack weights into MFMA B-fragment order ----------------
// Bp[l][ct][kc][lane][8]: ct 0..23 = Ut col-tiles (col = (ct%24)*16 + lane&15),
// ct 24..47 = whh col-tiles; kc = K-chunk of 32; lane fragment = 8 bf16 at
// k = kc*32 + (lane>>4)*8.
__global__ void pack_b_k(const unsigned short* __restrict__ Ut,
                         const void* __restrict__ whh,
                         unsigned short* __restrict__ Bp,
                         const int* __restrict__ flags) {
    int idx = blockIdx.x * 256 + threadIdx.x;  // 3*48*4*64 total
    if (idx >= 3 * 48 * 4 * 64) return;
    int l = idx / 12288;
    int rem = idx % 12288;
    int ct = rem >> 8;
    int kc = (rem >> 6) & 3;
    int lane = rem & 63;
    int col = (ct % 24) * 16 + (lane & 15);
    int k = kc * 32 + (lane >> 4) * 8;
    unsigned short tmp[8];
    const unsigned short* src;
    if (ct < 24) {
        src = Ut + (size_t)l * 49152 + col * 128 + k;
    } else if (flags[0]) {
        src = (const unsigned short*)whh + (size_t)col * 128 + k;
    } else {
        const float* wf = (const float*)whh + (size_t)col * 128 + k;
        for (int i = 0; i < 8; i++) tmp[i] = f_to_bfu(wf[i]);
        src = tmp;
    }
    unsigned short* dst = Bp + (size_t)l * 98304 + ((size_t)(ct * 4 + kc) * 64 + lane) * 8;
    for (int i = 0; i < 8; i++) dst[i] = src[i];
}

// ---------------- aggregation: y[n,:] = sum_{e: dst=n} w_e * xb[src_e,:] ----------------

__global__ __launch_bounds__(256) void agg_k(const unsigned short* __restrict__ xb,
                                             const int* __restrict__ offs,
                                             const uint2* __restrict__ rec,
                                             unsigned short* __restrict__ y, int N) {
    int node = (int)((blockIdx.x * 256 + threadIdx.x) >> 4);
    int l16 = threadIdx.x & 15;
    if (node >= N) return;
    int b = offs[node];
    int e2 = offs[node + 1];
    const uint4* xp4 = (const uint4*)xb;  // row = 16 uint4
    float a0[8], a1[8];
#pragma unroll
    for (int i = 0; i < 8; i++) { a0[i] = 0.f; a1[i] = 0.f; }

    auto fma_row = [&](float* acc, uint4 v, float w) {
        acc[0] += w * __builtin_bit_cast(float, v.x << 16);
        acc[1] += w * __builtin_bit_cast(float, v.x & 0xffff0000u);
        acc[2] += w * __builtin_bit_cast(float, v.y << 16);
        acc[3] += w * __builtin_bit_cast(float, v.y & 0xffff0000u);
        acc[4] += w * __builtin_bit_cast(float, v.z << 16);
        acc[5] += w * __builtin_bit_cast(float, v.z & 0xffff0000u);
        acc[6] += w * __builtin_bit_cast(float, v.w << 16);
        acc[7] += w * __builtin_bit_cast(float, v.w & 0xffff0000u);
    };

    int e = b;
    for (; e + 4 <= e2; e += 4) {
        uint2 r0 = rec[e], r1 = rec[e + 1], r2 = rec[e + 2], r3 = rec[e + 3];
        uint4 v0 = xp4[(size_t)r0.x * 16 + l16];
        uint4 v1 = xp4[(size_t)r1.x * 16 + l16];
        uint4 v2 = xp4[(size_t)r2.x * 16 + l16];
        uint4 v3 = xp4[(size_t)r3.x * 16 + l16];
        fma_row(a0, v0, __builtin_bit_cast(float, r0.y));
        fma_row(a1, v1, __builtin_bit_cast(float, r1.y));
        fma_row(a0, v2, __builtin_bit_cast(float, r2.y));
        fma_row(a1, v3, __builtin_bit_cast(float, r3.y));
    }
    for (; e < e2; e++) {
        uint2 r = rec[e];
        uint4 v = xp4[(size_t)r.x * 16 + l16];
        fma_row(a0, v, __builtin_bit_cast(float, r.y));
    }

    uint4 o;
    o.x = (unsigned int)f_to_bfu(a0[0] + a1[0]) | ((unsigned int)f_to_bfu(a0[1] + a1[1]) << 16);
    o.y = (unsigned int)f_to_bfu(a0[2] + a1[2]) | ((unsigned int)f_to_bfu(a0[3] + a1[3]) << 16);
    o.z = (unsigned int)f_to_bfu(a0[4] + a1[4]) | ((unsigned int)f_to_bfu(a0[5] + a1[5]) << 16);
    o.w = (unsigned int)f_to_bfu(a0[6] + a1[6]) | ((unsigned int)f_to_bfu(a0[7] + a1[7]) << 16);
    ((uint4*)y)[(size_t)node * 16 + l16] = o;
}

// ---------------- fused GRU: gi = y@Ut^T, gh = xin@whh^T, gates, write xout ----------------
// v2 (resubmit — round-1 bench was an infra failure, not a kernel verdict):
// M = 64 rows/block (4 row-tiles per wave). Each B-fragment load feeds 4 MFMAs
// (was 2) -> half the Bp L2 re-read and 4x arithmetic per load latency.
// __launch_bounds__(512,3): <=170 regs so the compiler can keep acc(96) +
// A-frags(32) + B-frags(24) in registers and batch the loads (old version sat
// at VGPR=52 with serialized load->mfma chains; MfmaUtil 8.3%).
// Epilogue: folded r/z biases; sigmoid = rcp(1+exp(-x)); tanh = 1-2*rcp(1+exp(2x))
// (saturation-safe both directions, err ~1e-6 << bf16 rounding).

__global__ __launch_bounds__(512, 3) void gru_k(const unsigned short* __restrict__ y,
                                                const unsigned short* __restrict__ xin,
                                                unsigned short* __restrict__ xout,
                                                const unsigned short* __restrict__ Bp,
                                                const float* __restrict__ bih,
                                                const float* __restrict__ bhh, int N) {
    int tid = threadIdx.x;
    int wave = tid >> 6;   // 0..7 = 16-channel col-tile
    int lane = tid & 63;
    int quad = lane >> 4;
    int m16 = lane & 15;
    int row0 = blockIdx.x * 64;

    floatx4 acc[4][6];  // [rt][g*2+p], p=0 -> gi (Ut), p=1 -> gh (whh)
#pragma unroll
    for (int rt = 0; rt < 4; rt++)
#pragma unroll
        for (int m = 0; m < 6; m++) acc[rt][m] = (floatx4){0.f, 0.f, 0.f, 0.f};

    int rA[4];
#pragma unroll
    for (int rt = 0; rt < 4; rt++) {
        int r = row0 + rt * 16 + m16;
        rA[rt] = (r < N) ? r : N - 1;
    }

#pragma unroll
    for (int kc = 0; kc < 4; kc++) {
        int ko = kc * 32 + quad * 8;
        bf16x8 aY[4], aX[4];
#pragma unroll
        for (int rt = 0; rt < 4; rt++) {
            aY[rt] = *(const bf16x8*)(y + (size_t)rA[rt] * 128 + ko);
            aX[rt] = *(const bf16x8*)(xin + (size_t)rA[rt] * 128 + ko);
        }
        bf16x8 bU[3], bW[3];
#pragma unroll
        for (int g = 0; g < 3; g++) {
            int ctU = g * 8 + wave;
            int ctW = 24 + g * 8 + wave;
            bU[g] = *(const bf16x8*)(Bp + ((size_t)(ctU * 4 + kc) * 64 + lane) * 8);
            bW[g] = *(const bf16x8*)(Bp + ((size_t)(ctW * 4 + kc) * 64 + lane) * 8);
        }
#pragma unroll
        for (int g = 0; g < 3; g++) {
#pragma unroll
            for (int rt = 0; rt < 4; rt++) {
                acc[rt][g * 2 + 0] =
                    __builtin_amdgcn_mfma_f32_16x16x32_bf16(aY[rt], bU[g], acc[rt][g * 2 + 0], 0, 0, 0);
                acc[rt][g * 2 + 1] =
                    __builtin_amdgcn_mfma_f32_16x16x32_bf16(aX[rt], bW[g], acc[rt][g * 2 + 1], 0, 0, 0);
            }
        }
    }

    int ch = wave * 16 + m16;  // 0..127
    float b_r = bih[ch] + bhh[ch];
    float b_z = bih[128 + ch] + bhh[128 + ch];
    float bi_n = bih[256 + ch];
    float bh_n = bhh[256 + ch];
#pragma unroll
    for (int rt = 0; rt < 4; rt++) {
#pragma unroll
        for (int ri = 0; ri < 4; ri++) {
            int row = row0 + rt * 16 + quad * 4 + ri;
            if (row >= N) continue;
            float sr = acc[rt][0][ri] + acc[rt][1][ri] + b_r;
            float sz = acc[rt][2][ri] + acc[rt][3][ri] + b_z;
            float gn = acc[rt][4][ri] + bi_n;
            float hn = acc[rt][5][ri] + bh_n;
            float r = __builtin_amdgcn_rcpf(1.f + __expf(-sr));
            float zg = __builtin_amdgcn_rcpf(1.f + __expf(-sz));
            float x2 = gn + r * hn;
            float n = 1.f - 2.f * __builtin_amdgcn_rcpf(1.f + __expf(2.f * x2));
            float h = bfu_to_f(xin[(size_t)row * 128 + ch]);
            float o = n + zg * (h - n);
            xout[(size_t)row * 128 + ch] = f_to_bfu(o);
        }
    }
}

// ---------------- launch ----------------

extern "C" void kernel_launch(void* const* d_in, const int* in_sizes, int n_in,
                              void* d_out, int out_size, void* d_ws, size_t ws_size,
                              hipStream_t stream) {
    const int N = in_sizes[0] / 128;
    const int E = in_sizes[1];
    const int NB = (N + NPB - 1) >> NPB_SHIFT;

    const void* z = d_in[0];
    const void* ew = d_in[1];
    const void* weight = d_in[2];
    const void* wih = d_in[3];
    const void* whh = d_in[4];
    const void* bih = d_in[5];
    const void* bhh = d_in[6];
    const unsigned int* eiu = (const unsigned int*)d_in[7];

    // y (bf16 N*128 = 25.6MB) aliases d_out — dead before final out_k write.
    unsigned short* y = (unsigned short*)d_out;

    size_t off = 0;
    char* base = (char*)d_ws;
    auto carve = [&](size_t bytes) -> void* {
        void* p = base + off;
        off = (off + bytes + 255) & ~(size_t)255;
        return p;
    };
    unsigned short* xb = (unsigned short*)carve((size_t)N * 128 * 2);
    unsigned short* xb2 = (unsigned short*)carve((size_t)N * 128 * 2);
    uint2* rec8 = (uint2*)carve((size_t)E * 8);   // binned (src,w)
    int* dstA = (int*)carve((size_t)E * 4);       // binned dst
    uint2* rec = (uint2*)carve((size_t)E * 8);    // final CSR records
    int* offsets = (int*)carve((size_t)(N + 1) * 4);
    int* bucketCnt = (int*)carve(MAXNB * 4);
    int* bucketBase = (int*)carve((MAXNB + 1) * 4);
    int* bucketCursor = (int*)carve(MAXNB * 4);
    unsigned short* Ut = (unsigned short*)carve((size_t)3 * 384 * 128 * 2);
    unsigned short* Bp = (unsigned short*)carve((size_t)3 * 48 * 4 * 64 * 8 * 2);
    float* bih_f = (float*)carve(384 * 4);
    float* bhh_f = (float*)carve(384 * 4);
    int* flags = (int*)carve(256);

    detect_k<<<1, 64, 0, stream>>>((const unsigned short*)bih, eiu, flags);

    cvt_bf16_k<<<(N * 128 + 255) / 256, 256, 0, stream>>>(z, xb, N * 128, flags);
    cvt_bias_k<<<3, 256, 0, stream>>>(bih, bhh, bih_f, bhh_f, flags);

    // hierarchical CSR build
    hipMemsetAsync(bucketCnt, 0, MAXNB * 4, stream);
    int gbin = (E + TILE - 1) / TILE;
    count_k<<<gbin, 256, 0, stream>>>(eiu, bucketCnt, E, flags);
    scanB_k<<<1, MAXNB, 0, stream>>>(bucketCnt, bucketBase, bucketCursor, NB, E);
    bin_k<<<gbin, 256, 0, stream>>>(eiu, ew, bucketCursor, rec8, dstA, E, flags);
    csr_k<<<NB, NPB, 0, stream>>>(rec8, dstA, bucketBase, offsets, rec, N, E);

    make_ut_k<<<(3 * 384 * 128 + 255) / 256, 256, 0, stream>>>(weight, wih, Ut, flags);
    pack_b_k<<<(3 * 48 * 4 * 64 + 255) / 256, 256, 0, stream>>>(Ut, whh, Bp, flags);

    const unsigned short* cur = xb;
    unsigned short* nxt = xb2;
    for (int l = 0; l < 3; l++) {
        agg_k<<<(N + 15) / 16, 256, 0, stream>>>(cur, offsets, rec, y, N);
        gru_k<<<(N + 63) / 64, 512, 0, stream>>>(y, cur, nxt, Bp + (size_t)l * 98304,
                                                 bih_f, bhh_f, N);
        const unsigned short* tmp = cur;
        cur = nxt;
        nxt = (unsigned short*)tmp;
    }

    out_k<<<(N * 128 + 255) / 256, 256, 0, stream>>>(cur, d_out, N * 128, flags);
}

// Round 3
// 680.227 us; speedup vs baseline: 1.0767x; 1.0570x over previous
//
#include <hip/hip_runtime.h>

typedef __bf16 bf16x8 __attribute__((ext_vector_type(8)));
typedef float floatx4 __attribute__((ext_vector_type(4)));

#define NPB 256        // nodes per bucket (power of 2)
#define NPB_SHIFT 8
#define MAXNB 1024     // max buckets supported (N <= 262144)
#define TILE 4096      // edges per binning block (391 blocks @ E=1.6M -> all CUs busy)

static __device__ __forceinline__ float bfu_to_f(unsigned short u) {
    unsigned int x = ((unsigned int)u) << 16;
    return __builtin_bit_cast(float, x);
}
static __device__ __forceinline__ unsigned short f_to_bfu(float f) {
    unsigned int u = __builtin_bit_cast(unsigned int, f);
    unsigned int r = (u + 0x7fffu + ((u >> 16) & 1u)) >> 16;
    return (unsigned short)r;
}

// ---------------- dtype detection ----------------
__global__ void detect_k(const unsigned short* __restrict__ bih_u,
                         const unsigned int* __restrict__ ei_u,
                         int* __restrict__ flags) {
    if (threadIdx.x == 0 && blockIdx.x == 0) {
        int votes = 0;
        for (int i = 0; i < 64; i++) {
            unsigned short u = bih_u[2 * i];
            unsigned int ex = (u >> 7) & 0xFF;
            if (ex >= 64 && ex < 124) votes++;
        }
        flags[0] = (votes >= 48) ? 1 : 0;
        int zeros = 0;
        for (int i = 0; i < 64; i++) {
            if (ei_u[2 * i + 1] == 0u) zeros++;
        }
        flags[1] = (zeros == 64) ? 1 : 0;
    }
}

// ---------------- canonicalization ----------------

__global__ void cvt_bf16_k(const void* __restrict__ in, unsigned short* __restrict__ out,
                           int n, const int* __restrict__ flags) {
    int i = blockIdx.x * 256 + threadIdx.x;
    if (i >= n) return;
    if (flags[0]) out[i] = ((const unsigned short*)in)[i];
    else out[i] = f_to_bfu(((const float*)in)[i]);
}

__global__ void cvt_bias_k(const void* __restrict__ bih, const void* __restrict__ bhh,
                           float* __restrict__ bih_f, float* __restrict__ bhh_f,
                           const int* __restrict__ flags) {
    int i = blockIdx.x * 256 + threadIdx.x;
    if (i >= 768) return;
    const void* src = (i < 384) ? bih : bhh;
    int j = (i < 384) ? i : i - 384;
    float v = flags[0] ? bfu_to_f(((const unsigned short*)src)[j]) : ((const float*)src)[j];
    if (i < 384) bih_f[j] = v;
    else bhh_f[j] = v;
}

__global__ void out_k(const unsigned short* __restrict__ xb, void* __restrict__ out,
                      int n, const int* __restrict__ flags) {
    int i = blockIdx.x * 256 + threadIdx.x;
    if (i >= n) return;
    if (flags[0]) ((unsigned short*)out)[i] = xb[i];
    else ((float*)out)[i] = bfu_to_f(xb[i]);
}

// ---------------- hierarchical CSR build ----------------

static __device__ __forceinline__ int load_idx(const unsigned int* eiu, size_t pos, int is64) {
    return (int)eiu[is64 ? 2 * pos : pos];
}

__global__ __launch_bounds__(256) void count_k(const unsigned int* __restrict__ eiu,
                                               int* __restrict__ bucketCnt, int E,
                                               const int* __restrict__ flags) {
    __shared__ int cnt[MAXNB];
    int t = threadIdx.x;
    for (int b = t; b < MAXNB; b += 256) cnt[b] = 0;
    __syncthreads();
    int is64 = flags[1];
    int e0 = blockIdx.x * TILE;
    int e1 = min(e0 + TILE, E);
    for (int e = e0 + t; e < e1; e += 256) {
        int d = load_idx(eiu, (size_t)E + e, is64);
        atomicAdd(&cnt[d >> NPB_SHIFT], 1);
    }
    __syncthreads();
    for (int b = t; b < MAXNB; b += 256) {
        int c = cnt[b];
        if (c) atomicAdd(&bucketCnt[b], c);
    }
}

__global__ void scanB_k(const int* __restrict__ bucketCnt, int* __restrict__ bucketBase,
                        int* __restrict__ bucketCursor, int NB, int E) {
    __shared__ int sh[MAXNB];
    int t = threadIdx.x;  // 1024 threads
    int v = (t < NB) ? bucketCnt[t] : 0;
    sh[t] = v;
    __syncthreads();
    for (int off = 1; off < MAXNB; off <<= 1) {
        int u = (t >= off) ? sh[t - off] : 0;
        __syncthreads();
        sh[t] += u;
        __syncthreads();
    }
    if (t < NB) {
        int b = sh[t] - v;
        bucketBase[t] = b;
        bucketCursor[t] = b;
    }
    if (t == 0) bucketBase[NB] = E;
}

__global__ __launch_bounds__(256) void bin_k(const unsigned int* __restrict__ eiu,
                                             const void* __restrict__ ew,
                                             int* __restrict__ bucketCursor,
                                             uint2* __restrict__ rec8,
                                             int* __restrict__ dstA, int E,
                                             const int* __restrict__ flags) {
    __shared__ int cnt[MAXNB];
    __shared__ int basel[MAXNB];
    int t = threadIdx.x;
    for (int b = t; b < MAXNB; b += 256) cnt[b] = 0;
    __syncthreads();
    int is64 = flags[1];
    int isb = flags[0];
    int e0 = blockIdx.x * TILE;
    int e1 = min(e0 + TILE, E);
    for (int e = e0 + t; e < e1; e += 256) {
        int d = load_idx(eiu, (size_t)E + e, is64);
        atomicAdd(&cnt[d >> NPB_SHIFT], 1);
    }
    __syncthreads();
    for (int b = t; b < MAXNB; b += 256) {
        int c = cnt[b];
        basel[b] = c ? atomicAdd(&bucketCursor[b], c) : 0;
        cnt[b] = 0;
    }
    __syncthreads();
    for (int e = e0 + t; e < e1; e += 256) {
        int s = load_idx(eiu, (size_t)e, is64);
        int d = load_idx(eiu, (size_t)E + e, is64);
        float w = isb ? bfu_to_f(((const unsigned short*)ew)[e]) : ((const float*)ew)[e];
        int b = d >> NPB_SHIFT;
        int p = basel[b] + atomicAdd(&cnt[b], 1);
        dstA[p] = d;
        rec8[p] = make_uint2((unsigned int)s, __builtin_bit_cast(unsigned int, w));
    }
}

__global__ __launch_bounds__(256) void csr_k(const uint2* __restrict__ rec8,
                                             const int* __restrict__ dstA,
                                             const int* __restrict__ bucketBase,
                                             int* __restrict__ offsets,
                                             uint2* __restrict__ rec, int N, int E) {
    __shared__ int cnt[NPB];
    __shared__ int sh[NPB];
    __shared__ int cur[NPB];
    int t = threadIdx.x;
    int b = blockIdx.x;
    int n0 = b << NPB_SHIFT;
    int nodes = min(NPB, N - n0);
    int ebase = bucketBase[b];
    int ecnt = bucketBase[b + 1] - ebase;

    cnt[t] = 0;
    __syncthreads();
    for (int i = t; i < ecnt; i += 256) {
        int d = dstA[ebase + i] - n0;
        atomicAdd(&cnt[d], 1);
    }
    __syncthreads();
    int v = cnt[t];
    sh[t] = v;
    __syncthreads();
    for (int off = 1; off < NPB; off <<= 1) {
        int u = (t >= off) ? sh[t - off] : 0;
        __syncthreads();
        sh[t] += u;
        __syncthreads();
    }
    int loff = sh[t] - v;  // exclusive
    if (t < nodes) offsets[n0 + t] = ebase + loff;
    cur[t] = ebase + loff;
    if (b == 0 && t == 0) offsets[N] = E;
    __syncthreads();
    for (int i = t; i < ecnt; i += 256) {
        int d = dstA[ebase + i] - n0;
        int p = atomicAdd(&cur[d], 1);
        rec[p] = rec8[ebase + i];
    }
}

// ---------------- Ut_l[j][a] = sum_k W_l[a][k] * w_ih[j][k] ----------------

static __device__ __forceinline__ float dot8_bf(uint4 wv, uint4 iv) {
    float s;
    s  = bfu_to_f((unsigned short)(wv.x)) * bfu_to_f((unsigned short)(iv.x));
    s += bfu_to_f((unsigned short)(wv.x >> 16)) * bfu_to_f((unsigned short)(iv.x >> 16));
    s += bfu_to_f((unsigned short)(wv.y)) * bfu_to_f((unsigned short)(iv.y));
    s += bfu_to_f((unsigned short)(wv.y >> 16)) * bfu_to_f((unsigned short)(iv.y >> 16));
    s += bfu_to_f((unsigned short)(wv.z)) * bfu_to_f((unsigned short)(iv.z));
    s += bfu_to_f((unsigned short)(wv.z >> 16)) * bfu_to_f((unsigned short)(iv.z >> 16));
    s += bfu_to_f((unsigned short)(wv.w)) * bfu_to_f((unsigned short)(iv.w));
    s += bfu_to_f((unsigned short)(wv.w >> 16)) * bfu_to_f((unsigned short)(iv.w >> 16));
    return s;
}

__global__ void make_ut_k(const void* __restrict__ weight, const void* __restrict__ wih,
                          unsigned short* __restrict__ Ut, const int* __restrict__ flags) {
    int idx = blockIdx.x * 256 + threadIdx.x;  // l*49152 + j*128 + a
    if (idx >= 3 * 384 * 128) return;
    int isb = flags[0];
    int a = idx & 127;
    int j = (idx >> 7) % 384;
    int l = idx / (384 * 128);
    float s = 0.f;
    if (isb) {
        const uint4* W4 = (const uint4*)((const unsigned short*)weight + (size_t)l * 16384 + a * 128);
        const uint4* I4 = (const uint4*)((const unsigned short*)wih + (size_t)j * 128);
#pragma unroll
        for (int c = 0; c < 16; c++) s += dot8_bf(W4[c], I4[c]);
    } else {
        const float4* W4 = (const float4*)((const float*)weight + (size_t)l * 16384 + a * 128);
        const float4* I4 = (const float4*)((const float*)wih + (size_t)j * 128);
#pragma unroll
        for (int c = 0; c < 32; c++) {
            float4 w = W4[c], i = I4[c];
            s += w.x * i.x + w.y * i.y + w.z * i.z + w.w * i.w;
        }
    }
    Ut[idx] = f_to_bfu(s);
}

// ---------------- pack weights into MFMA B-fragment order ----------------
// Bp[l][ct][kc][lane][8]: ct 0..23 = Ut col-tiles (col = (ct%24)*16 + lane&15),
// ct 24..47 = whh col-tiles; kc = K-chunk of 32; lane fragment = 8 bf16 at
// k = kc*32 + (lane>>4)*8.
__global__ void pack_b_k(const unsigned short* __restrict__ Ut,
                         const void* __restrict__ whh,
                         unsigned short* __restrict__ Bp,
                         const int* __restrict__ flags) {
    int idx = blockIdx.x * 256 + threadIdx.x;  // 3*48*4*64 total
    if (idx >= 3 * 48 * 4 * 64) return;
    int l = idx / 12288;
    int rem = idx % 12288;
    int ct = rem >> 8;
    int kc = (rem >> 6) & 3;
    int lane = rem & 63;
    int col = (ct % 24) * 16 + (lane & 15);
    int k = kc * 32 + (lane >> 4) * 8;
    unsigned short tmp[8];
    const unsigned short* src;
    if (ct < 24) {
        src = Ut + (size_t)l * 49152 + col * 128 + k;
    } else if (flags[0]) {
        src = (const unsigned short*)whh + (size_t)col * 128 + k;
    } else {
        const float* wf = (const float*)whh + (size_t)col * 128 + k;
        for (int i = 0; i < 8; i++) tmp[i] = f_to_bfu(wf[i]);
        src = tmp;
    }
    unsigned short* dst = Bp + (size_t)l * 98304 + ((size_t)(ct * 4 + kc) * 64 + lane) * 8;
    for (int i = 0; i < 8; i++) dst[i] = src[i];
}

// ---------------- aggregation: y[n,:] = sum_{e: dst=n} w_e * xb[src_e,:] ----------------

__global__ __launch_bounds__(256) void agg_k(const unsigned short* __restrict__ xb,
                                             const int* __restrict__ offs,
                                             const uint2* __restrict__ rec,
                                             unsigned short* __restrict__ y, int N) {
    int node = (int)((blockIdx.x * 256 + threadIdx.x) >> 4);
    int l16 = threadIdx.x & 15;
    if (node >= N) return;
    int b = offs[node];
    int e2 = offs[node + 1];
    const uint4* xp4 = (const uint4*)xb;  // row = 16 uint4
    float a0[8], a1[8];
#pragma unroll
    for (int i = 0; i < 8; i++) { a0[i] = 0.f; a1[i] = 0.f; }

    auto fma_row = [&](float* acc, uint4 v, float w) {
        acc[0] += w * __builtin_bit_cast(float, v.x << 16);
        acc[1] += w * __builtin_bit_cast(float, v.x & 0xffff0000u);
        acc[2] += w * __builtin_bit_cast(float, v.y << 16);
        acc[3] += w * __builtin_bit_cast(float, v.y & 0xffff0000u);
        acc[4] += w * __builtin_bit_cast(float, v.z << 16);
        acc[5] += w * __builtin_bit_cast(float, v.z & 0xffff0000u);
        acc[6] += w * __builtin_bit_cast(float, v.w << 16);
        acc[7] += w * __builtin_bit_cast(float, v.w & 0xffff0000u);
    };

    int e = b;
    for (; e + 4 <= e2; e += 4) {
        uint2 r0 = rec[e], r1 = rec[e + 1], r2 = rec[e + 2], r3 = rec[e + 3];
        uint4 v0 = xp4[(size_t)r0.x * 16 + l16];
        uint4 v1 = xp4[(size_t)r1.x * 16 + l16];
        uint4 v2 = xp4[(size_t)r2.x * 16 + l16];
        uint4 v3 = xp4[(size_t)r3.x * 16 + l16];
        fma_row(a0, v0, __builtin_bit_cast(float, r0.y));
        fma_row(a1, v1, __builtin_bit_cast(float, r1.y));
        fma_row(a0, v2, __builtin_bit_cast(float, r2.y));
        fma_row(a1, v3, __builtin_bit_cast(float, r3.y));
    }
    for (; e < e2; e++) {
        uint2 r = rec[e];
        uint4 v = xp4[(size_t)r.x * 16 + l16];
        fma_row(a0, v, __builtin_bit_cast(float, r.y));
    }

    uint4 o;
    o.x = (unsigned int)f_to_bfu(a0[0] + a1[0]) | ((unsigned int)f_to_bfu(a0[1] + a1[1]) << 16);
    o.y = (unsigned int)f_to_bfu(a0[2] + a1[2]) | ((unsigned int)f_to_bfu(a0[3] + a1[3]) << 16);
    o.z = (unsigned int)f_to_bfu(a0[4] + a1[4]) | ((unsigned int)f_to_bfu(a0[5] + a1[5]) << 16);
    o.w = (unsigned int)f_to_bfu(a0[6] + a1[6]) | ((unsigned int)f_to_bfu(a0[7] + a1[7]) << 16);
    ((uint4*)y)[(size_t)node * 16 + l16] = o;
}

// ---------------- fused GRU: gi = y@Ut^T, gh = xin@whh^T, gates, write xout ----------------
// v3: occupancy fix. Round-2 post-mortem: M=64 held acc[4][6] = 96 AGPRs +
// 84 VGPRs ~= 180 regs on the unified gfx950 file -> 2 waves/SIMD (Occ 19%),
// identical 92.7us as v1 -> latency-bound plateau, not VALU/ILP.
// Key algebra: only the n-gate needs gi and gh separate; r/z gates only ever
// use gi+gh, and MFMA accumulates in place -> acc_r += y*Ut_r; acc_r += x*whh_r
// in the SAME accumulator. 6 -> 4 accs per row-tile. With M=32 (2 row-tiles):
// acc[2][4] = 32 AGPRs, ~70 VGPRs, total ~= 100-110 -> 4 waves/SIMD
// (__launch_bounds__(512,4)). Same FLOPs, same B reuse per load as v1, but
// 2x the resident waves to hide the ~400-500cy L2/L3 A-load latency.

__global__ __launch_bounds__(512, 4) void gru_k(const unsigned short* __restrict__ y,
                                                const unsigned short* __restrict__ xin,
                                                unsigned short* __restrict__ xout,
                                                const unsigned short* __restrict__ Bp,
                                                const float* __restrict__ bih,
                                                const float* __restrict__ bhh, int N) {
    int tid = threadIdx.x;
    int wave = tid >> 6;   // 0..7 = 16-channel col-tile
    int lane = tid & 63;
    int quad = lane >> 4;
    int m16 = lane & 15;
    int row0 = blockIdx.x * 32;

    // acc[rt][s]: s=0 -> r (gi+gh fused), s=1 -> z (fused), s=2 -> gi_n, s=3 -> gh_n
    floatx4 acc[2][4];
#pragma unroll
    for (int rt = 0; rt < 2; rt++)
#pragma unroll
        for (int s = 0; s < 4; s++) acc[rt][s] = (floatx4){0.f, 0.f, 0.f, 0.f};

    int rA[2];
#pragma unroll
    for (int rt = 0; rt < 2; rt++) {
        int r = row0 + rt * 16 + m16;
        rA[rt] = (r < N) ? r : N - 1;
    }

#pragma unroll
    for (int kc = 0; kc < 4; kc++) {
        int ko = kc * 32 + quad * 8;
        bf16x8 aY[2], aX[2];
#pragma unroll
        for (int rt = 0; rt < 2; rt++) {
            aY[rt] = *(const bf16x8*)(y + (size_t)rA[rt] * 128 + ko);
            aX[rt] = *(const bf16x8*)(xin + (size_t)rA[rt] * 128 + ko);
        }
        bf16x8 bU[3], bW[3];
#pragma unroll
        for (int g = 0; g < 3; g++) {
            int ctU = g * 8 + wave;
            int ctW = 24 + g * 8 + wave;
            bU[g] = *(const bf16x8*)(Bp + ((size_t)(ctU * 4 + kc) * 64 + lane) * 8);
            bW[g] = *(const bf16x8*)(Bp + ((size_t)(ctW * 4 + kc) * 64 + lane) * 8);
        }
#pragma unroll
        for (int rt = 0; rt < 2; rt++) {
            // r gate: fused gi+gh accumulator
            acc[rt][0] = __builtin_amdgcn_mfma_f32_16x16x32_bf16(aY[rt], bU[0], acc[rt][0], 0, 0, 0);
            acc[rt][0] = __builtin_amdgcn_mfma_f32_16x16x32_bf16(aX[rt], bW[0], acc[rt][0], 0, 0, 0);
            // z gate: fused
            acc[rt][1] = __builtin_amdgcn_mfma_f32_16x16x32_bf16(aY[rt], bU[1], acc[rt][1], 0, 0, 0);
            acc[rt][1] = __builtin_amdgcn_mfma_f32_16x16x32_bf16(aX[rt], bW[1], acc[rt][1], 0, 0, 0);
            // n gate: keep gi / gh separate
            acc[rt][2] = __builtin_amdgcn_mfma_f32_16x16x32_bf16(aY[rt], bU[2], acc[rt][2], 0, 0, 0);
            acc[rt][3] = __builtin_amdgcn_mfma_f32_16x16x32_bf16(aX[rt], bW[2], acc[rt][3], 0, 0, 0);
        }
    }

    int ch = wave * 16 + m16;  // 0..127
    float b_r = bih[ch] + bhh[ch];
    float b_z = bih[128 + ch] + bhh[128 + ch];
    float bi_n = bih[256 + ch];
    float bh_n = bhh[256 + ch];
#pragma unroll
    for (int rt = 0; rt < 2; rt++) {
#pragma unroll
        for (int ri = 0; ri < 4; ri++) {
            int row = row0 + rt * 16 + quad * 4 + ri;
            if (row >= N) continue;
            float sr = acc[rt][0][ri] + b_r;
            float sz = acc[rt][1][ri] + b_z;
            float gn = acc[rt][2][ri] + bi_n;
            float hn = acc[rt][3][ri] + bh_n;
            float r = __builtin_amdgcn_rcpf(1.f + __expf(-sr));
            float zg = __builtin_amdgcn_rcpf(1.f + __expf(-sz));
            float x2 = gn + r * hn;
            float n = 1.f - 2.f * __builtin_amdgcn_rcpf(1.f + __expf(2.f * x2));
            float h = bfu_to_f(xin[(size_t)row * 128 + ch]);
            float o = n + zg * (h - n);
            xout[(size_t)row * 128 + ch] = f_to_bfu(o);
        }
    }
}

// ---------------- launch ----------------

extern "C" void kernel_launch(void* const* d_in, const int* in_sizes, int n_in,
                              void* d_out, int out_size, void* d_ws, size_t ws_size,
                              hipStream_t stream) {
    const int N = in_sizes[0] / 128;
    const int E = in_sizes[1];
    const int NB = (N + NPB - 1) >> NPB_SHIFT;

    const void* z = d_in[0];
    const void* ew = d_in[1];
    const void* weight = d_in[2];
    const void* wih = d_in[3];
    const void* whh = d_in[4];
    const void* bih = d_in[5];
    const void* bhh = d_in[6];
    const unsigned int* eiu = (const unsigned int*)d_in[7];

    // y (bf16 N*128 = 25.6MB) aliases d_out — dead before final out_k write.
    unsigned short* y = (unsigned short*)d_out;

    size_t off = 0;
    char* base = (char*)d_ws;
    auto carve = [&](size_t bytes) -> void* {
        void* p = base + off;
        off = (off + bytes + 255) & ~(size_t)255;
        return p;
    };
    unsigned short* xb = (unsigned short*)carve((size_t)N * 128 * 2);
    unsigned short* xb2 = (unsigned short*)carve((size_t)N * 128 * 2);
    uint2* rec8 = (uint2*)carve((size_t)E * 8);   // binned (src,w)
    int* dstA = (int*)carve((size_t)E * 4);       // binned dst
    uint2* rec = (uint2*)carve((size_t)E * 8);    // final CSR records
    int* offsets = (int*)carve((size_t)(N + 1) * 4);
    int* bucketCnt = (int*)carve(MAXNB * 4);
    int* bucketBase = (int*)carve((MAXNB + 1) * 4);
    int* bucketCursor = (int*)carve(MAXNB * 4);
    unsigned short* Ut = (unsigned short*)carve((size_t)3 * 384 * 128 * 2);
    unsigned short* Bp = (unsigned short*)carve((size_t)3 * 48 * 4 * 64 * 8 * 2);
    float* bih_f = (float*)carve(384 * 4);
    float* bhh_f = (float*)carve(384 * 4);
    int* flags = (int*)carve(256);

    detect_k<<<1, 64, 0, stream>>>((const unsigned short*)bih, eiu, flags);

    cvt_bf16_k<<<(N * 128 + 255) / 256, 256, 0, stream>>>(z, xb, N * 128, flags);
    cvt_bias_k<<<3, 256, 0, stream>>>(bih, bhh, bih_f, bhh_f, flags);

    // hierarchical CSR build
    hipMemsetAsync(bucketCnt, 0, MAXNB * 4, stream);
    int gbin = (E + TILE - 1) / TILE;
    count_k<<<gbin, 256, 0, stream>>>(eiu, bucketCnt, E, flags);
    scanB_k<<<1, MAXNB, 0, stream>>>(bucketCnt, bucketBase, bucketCursor, NB, E);
    bin_k<<<gbin, 256, 0, stream>>>(eiu, ew, bucketCursor, rec8, dstA, E, flags);
    csr_k<<<NB, NPB, 0, stream>>>(rec8, dstA, bucketBase, offsets, rec, N, E);

    make_ut_k<<<(3 * 384 * 128 + 255) / 256, 256, 0, stream>>>(weight, wih, Ut, flags);
    pack_b_k<<<(3 * 48 * 4 * 64 + 255) / 256, 256, 0, stream>>>(Ut, whh, Bp, flags);

    const unsigned short* cur = xb;
    unsigned short* nxt = xb2;
    for (int l = 0; l < 3; l++) {
        agg_k<<<(N + 15) / 16, 256, 0, stream>>>(cur, offsets, rec, y, N);
        gru_k<<<(N + 31) / 32, 512, 0, stream>>>(y, cur, nxt, Bp + (size_t)l * 98304,
                                                 bih_f, bhh_f, N);
        const unsigned short* tmp = cur;
        cur = nxt;
        nxt = (unsigned short*)tmp;
    }

    out_k<<<(N * 128 + 255) / 256, 256, 0, stream>>>(cur, d_out, N * 128, flags);
}

// Round 4
// 652.466 us; speedup vs baseline: 1.1225x; 1.0425x over previous
//
#include <hip/hip_runtime.h>

typedef __bf16 bf16x8 __attribute__((ext_vector_type(8)));
typedef float floatx4 __attribute__((ext_vector_type(4)));

#define NPB 256        // nodes per bucket (power of 2)
#define NPB_SHIFT 8
#define MAXNB 1024     // max buckets supported (N <= 262144)
#define TILE 4096      // edges per binning block (391 blocks @ E=1.6M -> all CUs busy)

static __device__ __forceinline__ float bfu_to_f(unsigned short u) {
    unsigned int x = ((unsigned int)u) << 16;
    return __builtin_bit_cast(float, x);
}
static __device__ __forceinline__ unsigned short f_to_bfu(float f) {
    unsigned int u = __builtin_bit_cast(unsigned int, f);
    unsigned int r = (u + 0x7fffu + ((u >> 16) & 1u)) >> 16;
    return (unsigned short)r;
}

// ---------------- dtype detection ----------------
__global__ void detect_k(const unsigned short* __restrict__ bih_u,
                         const unsigned int* __restrict__ ei_u,
                         int* __restrict__ flags) {
    if (threadIdx.x == 0 && blockIdx.x == 0) {
        int votes = 0;
        for (int i = 0; i < 64; i++) {
            unsigned short u = bih_u[2 * i];
            unsigned int ex = (u >> 7) & 0xFF;
            if (ex >= 64 && ex < 124) votes++;
        }
        flags[0] = (votes >= 48) ? 1 : 0;
        int zeros = 0;
        for (int i = 0; i < 64; i++) {
            if (ei_u[2 * i + 1] == 0u) zeros++;
        }
        flags[1] = (zeros == 64) ? 1 : 0;
    }
}

// ---------------- canonicalization ----------------

__global__ void cvt_bf16_k(const void* __restrict__ in, unsigned short* __restrict__ out,
                           int n, const int* __restrict__ flags) {
    int i = blockIdx.x * 256 + threadIdx.x;
    if (i >= n) return;
    if (flags[0]) out[i] = ((const unsigned short*)in)[i];
    else out[i] = f_to_bfu(((const float*)in)[i]);
}

__global__ void cvt_bias_k(const void* __restrict__ bih, const void* __restrict__ bhh,
                           float* __restrict__ bih_f, float* __restrict__ bhh_f,
                           const int* __restrict__ flags) {
    int i = blockIdx.x * 256 + threadIdx.x;
    if (i >= 768) return;
    const void* src = (i < 384) ? bih : bhh;
    int j = (i < 384) ? i : i - 384;
    float v = flags[0] ? bfu_to_f(((const unsigned short*)src)[j]) : ((const float*)src)[j];
    if (i < 384) bih_f[j] = v;
    else bhh_f[j] = v;
}

__global__ void out_k(const unsigned short* __restrict__ xb, void* __restrict__ out,
                      int n, const int* __restrict__ flags) {
    int i = blockIdx.x * 256 + threadIdx.x;
    if (i >= n) return;
    if (flags[0]) ((unsigned short*)out)[i] = xb[i];
    else ((float*)out)[i] = bfu_to_f(xb[i]);
}

// ---------------- hierarchical CSR build ----------------

static __device__ __forceinline__ int load_idx(const unsigned int* eiu, size_t pos, int is64) {
    return (int)eiu[is64 ? 2 * pos : pos];
}

__global__ __launch_bounds__(256) void count_k(const unsigned int* __restrict__ eiu,
                                               int* __restrict__ bucketCnt, int E,
                                               const int* __restrict__ flags) {
    __shared__ int cnt[MAXNB];
    int t = threadIdx.x;
    for (int b = t; b < MAXNB; b += 256) cnt[b] = 0;
    __syncthreads();
    int is64 = flags[1];
    int e0 = blockIdx.x * TILE;
    int e1 = min(e0 + TILE, E);
    for (int e = e0 + t; e < e1; e += 256) {
        int d = load_idx(eiu, (size_t)E + e, is64);
        atomicAdd(&cnt[d >> NPB_SHIFT], 1);
    }
    __syncthreads();
    for (int b = t; b < MAXNB; b += 256) {
        int c = cnt[b];
        if (c) atomicAdd(&bucketCnt[b], c);
    }
}

__global__ void scanB_k(const int* __restrict__ bucketCnt, int* __restrict__ bucketBase,
                        int* __restrict__ bucketCursor, int NB, int E) {
    __shared__ int sh[MAXNB];
    int t = threadIdx.x;  // 1024 threads
    int v = (t < NB) ? bucketCnt[t] : 0;
    sh[t] = v;
    __syncthreads();
    for (int off = 1; off < MAXNB; off <<= 1) {
        int u = (t >= off) ? sh[t - off] : 0;
        __syncthreads();
        sh[t] += u;
        __syncthreads();
    }
    if (t < NB) {
        int b = sh[t] - v;
        bucketBase[t] = b;
        bucketCursor[t] = b;
    }
    if (t == 0) bucketBase[NB] = E;
}

__global__ __launch_bounds__(256) void bin_k(const unsigned int* __restrict__ eiu,
                                             const void* __restrict__ ew,
                                             int* __restrict__ bucketCursor,
                                             uint2* __restrict__ rec8,
                                             int* __restrict__ dstA, int E,
                                             const int* __restrict__ flags) {
    __shared__ int cnt[MAXNB];
    __shared__ int basel[MAXNB];
    int t = threadIdx.x;
    for (int b = t; b < MAXNB; b += 256) cnt[b] = 0;
    __syncthreads();
    int is64 = flags[1];
    int isb = flags[0];
    int e0 = blockIdx.x * TILE;
    int e1 = min(e0 + TILE, E);
    for (int e = e0 + t; e < e1; e += 256) {
        int d = load_idx(eiu, (size_t)E + e, is64);
        atomicAdd(&cnt[d >> NPB_SHIFT], 1);
    }
    __syncthreads();
    for (int b = t; b < MAXNB; b += 256) {
        int c = cnt[b];
        basel[b] = c ? atomicAdd(&bucketCursor[b], c) : 0;
        cnt[b] = 0;
    }
    __syncthreads();
    for (int e = e0 + t; e < e1; e += 256) {
        int s = load_idx(eiu, (size_t)e, is64);
        int d = load_idx(eiu, (size_t)E + e, is64);
        float w = isb ? bfu_to_f(((const unsigned short*)ew)[e]) : ((const float*)ew)[e];
        int b = d >> NPB_SHIFT;
        int p = basel[b] + atomicAdd(&cnt[b], 1);
        dstA[p] = d;
        rec8[p] = make_uint2((unsigned int)s, __builtin_bit_cast(unsigned int, w));
    }
}

__global__ __launch_bounds__(256) void csr_k(const uint2* __restrict__ rec8,
                                             const int* __restrict__ dstA,
                                             const int* __restrict__ bucketBase,
                                             int* __restrict__ offsets,
                                             uint2* __restrict__ rec, int N, int E) {
    __shared__ int cnt[NPB];
    __shared__ int sh[NPB];
    __shared__ int cur[NPB];
    int t = threadIdx.x;
    int b = blockIdx.x;
    int n0 = b << NPB_SHIFT;
    int nodes = min(NPB, N - n0);
    int ebase = bucketBase[b];
    int ecnt = bucketBase[b + 1] - ebase;

    cnt[t] = 0;
    __syncthreads();
    for (int i = t; i < ecnt; i += 256) {
        int d = dstA[ebase + i] - n0;
        atomicAdd(&cnt[d], 1);
    }
    __syncthreads();
    int v = cnt[t];
    sh[t] = v;
    __syncthreads();
    for (int off = 1; off < NPB; off <<= 1) {
        int u = (t >= off) ? sh[t - off] : 0;
        __syncthreads();
        sh[t] += u;
        __syncthreads();
    }
    int loff = sh[t] - v;  // exclusive
    if (t < nodes) offsets[n0 + t] = ebase + loff;
    cur[t] = ebase + loff;
    if (b == 0 && t == 0) offsets[N] = E;
    __syncthreads();
    for (int i = t; i < ecnt; i += 256) {
        int d = dstA[ebase + i] - n0;
        int p = atomicAdd(&cur[d], 1);
        rec[p] = rec8[ebase + i];
    }
}

// ---------------- Ut_l[j][a] = sum_k W_l[a][k] * w_ih[j][k] ----------------

static __device__ __forceinline__ float dot8_bf(uint4 wv, uint4 iv) {
    float s;
    s  = bfu_to_f((unsigned short)(wv.x)) * bfu_to_f((unsigned short)(iv.x));
    s += bfu_to_f((unsigned short)(wv.x >> 16)) * bfu_to_f((unsigned short)(iv.x >> 16));
    s += bfu_to_f((unsigned short)(wv.y)) * bfu_to_f((unsigned short)(iv.y));
    s += bfu_to_f((unsigned short)(wv.y >> 16)) * bfu_to_f((unsigned short)(iv.y >> 16));
    s += bfu_to_f((unsigned short)(wv.z)) * bfu_to_f((unsigned short)(iv.z));
    s += bfu_to_f((unsigned short)(wv.z >> 16)) * bfu_to_f((unsigned short)(iv.z >> 16));
    s += bfu_to_f((unsigned short)(wv.w)) * bfu_to_f((unsigned short)(iv.w));
    s += bfu_to_f((unsigned short)(wv.w >> 16)) * bfu_to_f((unsigned short)(iv.w >> 16));
    return s;
}

__global__ void make_ut_k(const void* __restrict__ weight, const void* __restrict__ wih,
                          unsigned short* __restrict__ Ut, const int* __restrict__ flags) {
    int idx = blockIdx.x * 256 + threadIdx.x;  // l*49152 + j*128 + a
    if (idx >= 3 * 384 * 128) return;
    int isb = flags[0];
    int a = idx & 127;
    int j = (idx >> 7) % 384;
    int l = idx / (384 * 128);
    float s = 0.f;
    if (isb) {
        const uint4* W4 = (const uint4*)((const unsigned short*)weight + (size_t)l * 16384 + a * 128);
        const uint4* I4 = (const uint4*)((const unsigned short*)wih + (size_t)j * 128);
#pragma unroll
        for (int c = 0; c < 16; c++) s += dot8_bf(W4[c], I4[c]);
    } else {
        const float4* W4 = (const float4*)((const float*)weight + (size_t)l * 16384 + a * 128);
        const float4* I4 = (const float4*)((const float*)wih + (size_t)j * 128);
#pragma unroll
        for (int c = 0; c < 32; c++) {
            float4 w = W4[c], i = I4[c];
            s += w.x * i.x + w.y * i.y + w.z * i.z + w.w * i.w;
        }
    }
    Ut[idx] = f_to_bfu(s);
}

// ---------------- pack weights into MFMA B-fragment order (cg-major) ----------------
// v4 layout: Bp[l][cg][j][kc][lane][8], cg = 32-channel group (0..3),
// j = s*6 + g*2 + t: s 0=Ut 1=whh, g = gate (r,z,n), t = 16-ch tile within group.
// A gru block for channel group cg reads the contiguous 48KB slice [l][cg][...]
// into LDS once. Fragment innermost layout unchanged: lane covers
// col = (cg*2+t)*16 + (lane&15), k = kc*32 + (lane>>4)*8.
__global__ void pack_b_k(const unsigned short* __restrict__ Ut,
                         const void* __restrict__ whh,
                         unsigned short* __restrict__ Bp,
                         const int* __restrict__ flags) {
    int idx = blockIdx.x * 256 + threadIdx.x;  // 3*4*12*4*64 total
    if (idx >= 3 * 4 * 12 * 4 * 64) return;
    int lane = idx & 63;
    int kc = (idx >> 6) & 3;
    int rest = idx >> 8;           // l*48 + cg*12 + j
    int j = rest % 12;
    int cg = (rest / 12) & 3;
    int l = rest / 48;
    int s = j / 6;
    int g = (j % 6) >> 1;
    int t = j & 1;
    int col = (cg * 2 + t) * 16 + (lane & 15);   // 0..127
    int k = kc * 32 + (lane >> 4) * 8;
    (void)g;  // gate index is encoded in j's position; source col/k fully determine data
    unsigned short tmp[8];
    const unsigned short* src;
    if (s == 0) {
        // Ut rows are (gate*128 + col) in the 384-row Ut: row = g*128 + col? No:
        // Ut layout is [j=0..383][a=0..127] with j = gate*128 + channel? Ut was built
        // as Ut[l][jrow][a] where jrow 0..383 spans the 3 gates of w_ih rows.
        // Old pack used ct = gate*8 + tile -> col index into 384 via (ct%24)*16:
        // (g*8 + tile)*16 = g*128 + tile*16. Reproduce: row384 = g*128 + (cg*2+t)*16 + (lane&15).
        int row384 = (j % 6) >> 1;  // g
        row384 = row384 * 128 + col;
        src = Ut + (size_t)l * 49152 + row384 * 128 + k;
    } else if (flags[0]) {
        int row384 = ((j % 6) >> 1) * 128 + col;
        src = (const unsigned short*)whh + (size_t)row384 * 128 + k;
    } else {
        int row384 = ((j % 6) >> 1) * 128 + col;
        const float* wf = (const float*)whh + (size_t)row384 * 128 + k;
        for (int i = 0; i < 8; i++) tmp[i] = f_to_bfu(wf[i]);
        src = tmp;
    }
    unsigned short* dst = Bp + (size_t)l * 98304 + (((size_t)(cg * 12 + j) * 4 + kc) * 64 + lane) * 8;
    for (int i = 0; i < 8; i++) dst[i] = src[i];
}

// ---------------- aggregation: y[n,:] = sum_{e: dst=n} w_e * xb[src_e,:] ----------------

__global__ __launch_bounds__(256) void agg_k(const unsigned short* __restrict__ xb,
                                             const int* __restrict__ offs,
                                             const uint2* __restrict__ rec,
                                             unsigned short* __restrict__ y, int N) {
    int node = (int)((blockIdx.x * 256 + threadIdx.x) >> 4);
    int l16 = threadIdx.x & 15;
    if (node >= N) return;
    int b = offs[node];
    int e2 = offs[node + 1];
    const uint4* xp4 = (const uint4*)xb;  // row = 16 uint4
    float a0[8], a1[8];
#pragma unroll
    for (int i = 0; i < 8; i++) { a0[i] = 0.f; a1[i] = 0.f; }

    auto fma_row = [&](float* acc, uint4 v, float w) {
        acc[0] += w * __builtin_bit_cast(float, v.x << 16);
        acc[1] += w * __builtin_bit_cast(float, v.x & 0xffff0000u);
        acc[2] += w * __builtin_bit_cast(float, v.y << 16);
        acc[3] += w * __builtin_bit_cast(float, v.y & 0xffff0000u);
        acc[4] += w * __builtin_bit_cast(float, v.z << 16);
        acc[5] += w * __builtin_bit_cast(float, v.z & 0xffff0000u);
        acc[6] += w * __builtin_bit_cast(float, v.w << 16);
        acc[7] += w * __builtin_bit_cast(float, v.w & 0xffff0000u);
    };

    int e = b;
    for (; e + 4 <= e2; e += 4) {
        uint2 r0 = rec[e], r1 = rec[e + 1], r2 = rec[e + 2], r3 = rec[e + 3];
        uint4 v0 = xp4[(size_t)r0.x * 16 + l16];
        uint4 v1 = xp4[(size_t)r1.x * 16 + l16];
        uint4 v2 = xp4[(size_t)r2.x * 16 + l16];
        uint4 v3 = xp4[(size_t)r3.x * 16 + l16];
        fma_row(a0, v0, __builtin_bit_cast(float, r0.y));
        fma_row(a1, v1, __builtin_bit_cast(float, r1.y));
        fma_row(a0, v2, __builtin_bit_cast(float, r2.y));
        fma_row(a1, v3, __builtin_bit_cast(float, r3.y));
    }
    for (; e < e2; e++) {
        uint2 r = rec[e];
        uint4 v = xp4[(size_t)r.x * 16 + l16];
        fma_row(a0, v, __builtin_bit_cast(float, r.y));
    }

    uint4 o;
    o.x = (unsigned int)f_to_bfu(a0[0] + a1[0]) | ((unsigned int)f_to_bfu(a0[1] + a1[1]) << 16);
    o.y = (unsigned int)f_to_bfu(a0[2] + a1[2]) | ((unsigned int)f_to_bfu(a0[3] + a1[3]) << 16);
    o.z = (unsigned int)f_to_bfu(a0[4] + a1[4]) | ((unsigned int)f_to_bfu(a0[5] + a1[5]) << 16);
    o.w = (unsigned int)f_to_bfu(a0[6] + a1[6]) | ((unsigned int)f_to_bfu(a0[7] + a1[7]) << 16);
    ((uint4*)y)[(size_t)node * 16 + l16] = o;
}

// ---------------- fused GRU: gi = y@Ut^T, gh = xin@whh^T, gates, write xout ----------------
// v4: B in LDS. Round-3 post-mortem: still latency-bound (Mfma 9%, VALU 20%,
// HBM 8%, occ 39%) — per-kc batch of 6 B-loads (L2, 612MB/dispatch re-read)
// + 4 A-loads (L3) serializes against a frugal 48-VGPR allocation. Escape:
// split blocks by 32-channel group; the block's B slice is 48KB -> staged to
// LDS once; all B-reads become ds_read_b128 (lgkm, ~120cy, conflict-free).
// B L2 traffic 612MB -> 150MB. 8 waves: wave = wr*2+wc, wc = 16-ch tile in
// group, wr = 32-row slice; rows/block = 128, acc[2][4] = 32 AGPR.
// XCD-swizzled grid: the 4 cg-blocks of one row-block land on one XCD's L2
// (they read identical y/xin rows). launch_bounds(512,6): <=85 regs ->
// 3 blocks/CU (LDS 3x48KB=144 <= 160KB) = 75% occ target.

__global__ __launch_bounds__(512, 6) void gru_k(const unsigned short* __restrict__ y,
                                                const unsigned short* __restrict__ xin,
                                                unsigned short* __restrict__ xout,
                                                const unsigned short* __restrict__ Bp,
                                                const float* __restrict__ bih,
                                                const float* __restrict__ bhh, int N) {
    __shared__ uint4 Blds[3072];  // 48KB: [12][4][64] x 16B

    int bid = blockIdx.x;
    int r8 = bid & 7;
    int inner = bid >> 3;
    int cg = inner & 3;
    int rb = ((inner >> 2) << 3) + r8;
    int row0 = rb << 7;  // *128
    if (row0 >= N) return;

    int tid = threadIdx.x;
    int wave = tid >> 6;
    int wc = wave & 1;       // 16-ch tile within the 32-ch group
    int wr = wave >> 1;      // 0..3: 32-row slice
    int lane = tid & 63;
    int quad = lane >> 4;
    int m16 = lane & 15;

    // stage this cg's 48KB B slice
    {
        const uint4* bsrc = (const uint4*)(Bp + (size_t)cg * 24576);
#pragma unroll
        for (int i = 0; i < 6; i++) Blds[tid + i * 512] = bsrc[tid + i * 512];
    }
    __syncthreads();

    // acc[rt][s]: s=0 -> r (gi+gh fused), s=1 -> z (fused), s=2 -> gi_n, s=3 -> gh_n
    floatx4 acc[2][4];
#pragma unroll
    for (int rt = 0; rt < 2; rt++)
#pragma unroll
        for (int s = 0; s < 4; s++) acc[rt][s] = (floatx4){0.f, 0.f, 0.f, 0.f};

    int rA[2];
#pragma unroll
    for (int rt = 0; rt < 2; rt++) {
        int r = row0 + wr * 32 + rt * 16 + m16;
        rA[rt] = (r < N) ? r : N - 1;
    }

    const unsigned short* bl = (const unsigned short*)Blds;

#pragma unroll
    for (int kc = 0; kc < 4; kc++) {
        int ko = kc * 32 + quad * 8;
        bf16x8 aY[2], aX[2];
#pragma unroll
        for (int rt = 0; rt < 2; rt++) {
            aY[rt] = *(const bf16x8*)(y + (size_t)rA[rt] * 128 + ko);
            aX[rt] = *(const bf16x8*)(xin + (size_t)rA[rt] * 128 + ko);
        }
        bf16x8 bU[3], bW[3];
#pragma unroll
        for (int g = 0; g < 3; g++) {
            int jU = g * 2 + wc;        // s=0
            int jW = 6 + g * 2 + wc;    // s=1
            bU[g] = *(const bf16x8*)(bl + ((size_t)(jU * 4 + kc) * 64 + lane) * 8);
            bW[g] = *(const bf16x8*)(bl + ((size_t)(jW * 4 + kc) * 64 + lane) * 8);
        }
#pragma unroll
        for (int rt = 0; rt < 2; rt++) {
            acc[rt][0] = __builtin_amdgcn_mfma_f32_16x16x32_bf16(aY[rt], bU[0], acc[rt][0], 0, 0, 0);
            acc[rt][0] = __builtin_amdgcn_mfma_f32_16x16x32_bf16(aX[rt], bW[0], acc[rt][0], 0, 0, 0);
            acc[rt][1] = __builtin_amdgcn_mfma_f32_16x16x32_bf16(aY[rt], bU[1], acc[rt][1], 0, 0, 0);
            acc[rt][1] = __builtin_amdgcn_mfma_f32_16x16x32_bf16(aX[rt], bW[1], acc[rt][1], 0, 0, 0);
            acc[rt][2] = __builtin_amdgcn_mfma_f32_16x16x32_bf16(aY[rt], bU[2], acc[rt][2], 0, 0, 0);
            acc[rt][3] = __builtin_amdgcn_mfma_f32_16x16x32_bf16(aX[rt], bW[2], acc[rt][3], 0, 0, 0);
        }
    }

    int ch = cg * 32 + wc * 16 + m16;  // 0..127
    float b_r = bih[ch] + bhh[ch];
    float b_z = bih[128 + ch] + bhh[128 + ch];
    float bi_n = bih[256 + ch];
    float bh_n = bhh[256 + ch];
#pragma unroll
    for (int rt = 0; rt < 2; rt++) {
#pragma unroll
        for (int ri = 0; ri < 4; ri++) {
            int row = row0 + wr * 32 + rt * 16 + quad * 4 + ri;
            if (row >= N) continue;
            float sr = acc[rt][0][ri] + b_r;
            float sz = acc[rt][1][ri] + b_z;
            float gn = acc[rt][2][ri] + bi_n;
            float hn = acc[rt][3][ri] + bh_n;
            float r = __builtin_amdgcn_rcpf(1.f + __expf(-sr));
            float zg = __builtin_amdgcn_rcpf(1.f + __expf(-sz));
            float x2 = gn + r * hn;
            float n = 1.f - 2.f * __builtin_amdgcn_rcpf(1.f + __expf(2.f * x2));
            float h = bfu_to_f(xin[(size_t)row * 128 + ch]);
            float o = n + zg * (h - n);
            xout[(size_t)row * 128 + ch] = f_to_bfu(o);
        }
    }
}

// ---------------- launch ----------------

extern "C" void kernel_launch(void* const* d_in, const int* in_sizes, int n_in,
                              void* d_out, int out_size, void* d_ws, size_t ws_size,
                              hipStream_t stream) {
    const int N = in_sizes[0] / 128;
    const int E = in_sizes[1];
    const int NB = (N + NPB - 1) >> NPB_SHIFT;

    const void* z = d_in[0];
    const void* ew = d_in[1];
    const void* weight = d_in[2];
    const void* wih = d_in[3];
    const void* whh = d_in[4];
    const void* bih = d_in[5];
    const void* bhh = d_in[6];
    const unsigned int* eiu = (const unsigned int*)d_in[7];

    // y (bf16 N*128 = 25.6MB) aliases d_out — dead before final out_k write.
    unsigned short* y = (unsigned short*)d_out;

    size_t off = 0;
    char* base = (char*)d_ws;
    auto carve = [&](size_t bytes) -> void* {
        void* p = base + off;
        off = (off + bytes + 255) & ~(size_t)255;
        return p;
    };
    unsigned short* xb = (unsigned short*)carve((size_t)N * 128 * 2);
    unsigned short* xb2 = (unsigned short*)carve((size_t)N * 128 * 2);
    uint2* rec8 = (uint2*)carve((size_t)E * 8);   // binned (src,w)
    int* dstA = (int*)carve((size_t)E * 4);       // binned dst
    uint2* rec = (uint2*)carve((size_t)E * 8);    // final CSR records
    int* offsets = (int*)carve((size_t)(N + 1) * 4);
    int* bucketCnt = (int*)carve(MAXNB * 4);
    int* bucketBase = (int*)carve((MAXNB + 1) * 4);
    int* bucketCursor = (int*)carve(MAXNB * 4);
    unsigned short* Ut = (unsigned short*)carve((size_t)3 * 384 * 128 * 2);
    unsigned short* Bp = (unsigned short*)carve((size_t)3 * 48 * 4 * 64 * 8 * 2);
    float* bih_f = (float*)carve(384 * 4);
    float* bhh_f = (float*)carve(384 * 4);
    int* flags = (int*)carve(256);

    detect_k<<<1, 64, 0, stream>>>((const unsigned short*)bih, eiu, flags);

    cvt_bf16_k<<<(N * 128 + 255) / 256, 256, 0, stream>>>(z, xb, N * 128, flags);
    cvt_bias_k<<<3, 256, 0, stream>>>(bih, bhh, bih_f, bhh_f, flags);

    // hierarchical CSR build
    hipMemsetAsync(bucketCnt, 0, MAXNB * 4, stream);
    int gbin = (E + TILE - 1) / TILE;
    count_k<<<gbin, 256, 0, stream>>>(eiu, bucketCnt, E, flags);
    scanB_k<<<1, MAXNB, 0, stream>>>(bucketCnt, bucketBase, bucketCursor, NB, E);
    bin_k<<<gbin, 256, 0, stream>>>(eiu, ew, bucketCursor, rec8, dstA, E, flags);
    csr_k<<<NB, NPB, 0, stream>>>(rec8, dstA, bucketBase, offsets, rec, N, E);

    make_ut_k<<<(3 * 384 * 128 + 255) / 256, 256, 0, stream>>>(weight, wih, Ut, flags);
    pack_b_k<<<(3 * 4 * 12 * 4 * 64 + 255) / 256, 256, 0, stream>>>(Ut, whh, Bp, flags);

    // gru grid: XCD-swizzled (rb,cg) -> bid so the 4 cg-blocks of a row-block
    // share one XCD's L2. bid = (rb&7) + 8*((rb>>3)*4 + cg); guard rb>=RB.
    const int RB = (N + 127) >> 7;
    const int grid_gru = 8 * ((RB + 7) >> 3) * 4;

    const unsigned short* cur = xb;
    unsigned short* nxt = xb2;
    for (int l = 0; l < 3; l++) {
        agg_k<<<(N + 15) / 16, 256, 0, stream>>>(cur, offsets, rec, y, N);
        gru_k<<<grid_gru, 512, 0, stream>>>(y, cur, nxt, Bp + (size_t)l * 98304,
                                            bih_f, bhh_f, N);
        const unsigned short* tmp = cur;
        cur = nxt;
        nxt = (unsigned short*)tmp;
    }

    out_k<<<(N * 128 + 255) / 256, 256, 0, stream>>>(cur, d_out, N * 128, flags);
}